// Round 9
// baseline (392.133 us; speedup 1.0000x reference)
//
#include <hip/hip_runtime.h>
#include <math.h>

typedef float floatx2 __attribute__((ext_vector_type(2)));
typedef float floatx4 __attribute__((ext_vector_type(4)));
typedef short bf16x8 __attribute__((ext_vector_type(8)));
typedef _Float16 halfx2 __attribute__((ext_vector_type(2)));

#define NODE_MASK 0x07FFFFFF
#define LOG2E 1.4426950408889634f

__device__ __forceinline__ float wave_sum(float v){
#pragma unroll
  for (int m = 1; m < 64; m <<= 1) v += __shfl_xor(v, m, 64);
  return v;
}

__device__ __forceinline__ unsigned short bf16_of(float a){
  unsigned ua = __float_as_uint(a);
  ua = (ua + 0x7FFFu + ((ua >> 16) & 1u)) >> 16;
  return (unsigned short)ua;
}
__device__ __forceinline__ unsigned pack_bf16(float a, float b){
  unsigned ua = __float_as_uint(a), ub = __float_as_uint(b);
  ua = (ua + 0x7FFFu + ((ua >> 16) & 1u)) >> 16;
  ub = (ub + 0x7FFFu + ((ub >> 16) & 1u)) >> 16;
  return ua | (ub << 16);
}
__device__ __forceinline__ float2 unpack_bf16(unsigned p){
  float2 r;
  r.x = __uint_as_float(p << 16);
  r.y = __uint_as_float(p & 0xFFFF0000u);
  return r;
}
__device__ __forceinline__ bf16x8 to_bf16x8(float4 a, float4 b){
  bf16x8 r;
  r[0]=(short)bf16_of(a.x); r[1]=(short)bf16_of(a.y);
  r[2]=(short)bf16_of(a.z); r[3]=(short)bf16_of(a.w);
  r[4]=(short)bf16_of(b.x); r[5]=(short)bf16_of(b.y);
  r[6]=(short)bf16_of(b.z); r[7]=(short)bf16_of(b.w);
  return r;
}
__device__ __forceinline__ halfx2 f22h2(float a, float b){
  auto r = __builtin_amdgcn_cvt_pkrtz(a, b);
  return *(halfx2*)&r;
}
__device__ __forceinline__ float fdot2h(halfx2 a, halfx2 b, float c){
  return __builtin_amdgcn_fdot2(a, b, c, false);
}

// ---- merged: deg_rank (blocks >= NT64) || layer-0 node transform (blocks < NT64) ----
__global__ __launch_bounds__(256)
void k_deg_t0(const int* __restrict__ dst, int* __restrict__ deg, int* __restrict__ rank, int e,
              const float* __restrict__ h,
              const float* __restrict__ Wl, const float* __restrict__ bl,
              const float* __restrict__ Wr, const float* __restrict__ br,
              const float* __restrict__ Wres, const float* __restrict__ bias,
              unsigned short* __restrict__ xl8, float* __restrict__ xr,
              float* __restrict__ res, int n, int nt64){
  if ((int)blockIdx.x >= nt64){
    int c = blockIdx.x - nt64;
    int i = (c*256 + (int)threadIdx.x)*4;
    if (i + 3 < e){
      int4 d4 = *(const int4*)&dst[i];
      int4 r4;
      r4.x = atomicAdd(&deg[d4.x], 1);
      r4.y = atomicAdd(&deg[d4.y], 1);
      r4.z = atomicAdd(&deg[d4.z], 1);
      r4.w = atomicAdd(&deg[d4.w], 1);
      *(int4*)&rank[i] = r4;
    } else {
      for (int j = i; j < e; ++j) rank[j] = atomicAdd(&deg[dst[j]], 1);
    }
    return;
  }
  const int K = 32, KH = 1;
  int lane = threadIdx.x & 63;
  int nt   = threadIdx.x >> 6;
  int nn = lane & 15, q = lane >> 4;
  int m0 = blockIdx.x * 64;
  if (m0 >= n) return;
  bf16x8 Af[4][KH];
#pragma unroll
  for (int t = 0; t < 4; ++t){
#pragma unroll
    for (int kh = 0; kh < KH; ++kh){
      int node = min(m0 + t*16 + nn, n - 1);
      const float* hp = h + (size_t)node*K + kh*32 + q*8;
      Af[t][kh] = to_bf16x8(*(const float4*)hp, *(const float4*)(hp + 4));
    }
  }
  int n0 = nt * 16;
  for (int sel = 0; sel < 3; ++sel){
    const float* Wp = (sel == 0) ? Wl : (sel == 1) ? Wr : Wres;
    const float* bp = (sel == 0) ? bl : (sel == 1) ? br : bias;
    bf16x8 Bf[KH];
#pragma unroll
    for (int kh = 0; kh < KH; ++kh){
#pragma unroll
      for (int j = 0; j < 8; ++j)
        Bf[kh][j] = (short)bf16_of(Wp[(kh*32 + q*8 + j)*64 + n0 + nn]);
    }
    float bv = bp[n0 + nn];
#pragma unroll
    for (int t = 0; t < 4; ++t){
      floatx4 acc = {bv, bv, bv, bv};
#pragma unroll
      for (int kh = 0; kh < KH; ++kh)
        acc = __builtin_amdgcn_mfma_f32_16x16x32_bf16(Af[t][kh], Bf[kh], acc, 0, 0, 0);
      int nodeb = m0 + t*16 + q*4;
      if (sel == 0){
#pragma unroll
        for (int reg = 0; reg < 4; ++reg){
          float v = acc[reg];
          float p = __shfl_xor(v, 1, 64);
          int node = nodeb + reg;
          if (!(nn & 1) && node < n)
            xl8[(size_t)node*32 + ((n0 + nn) >> 1)] =
              (unsigned short)__builtin_amdgcn_cvt_pk_fp8_f32(v, p, 0, false);
        }
      } else {
        float* op = (sel == 1) ? xr : res;
#pragma unroll
        for (int reg = 0; reg < 4; ++reg){
          int node = nodeb + reg;
          if (node < n) op[(size_t)node*64 + n0 + nn] = acc[reg];
        }
      }
    }
  }
}

// block-sum of (deg+1) -> bsum[b]
__global__ void k_scan_reduce(const int* __restrict__ deg, int* __restrict__ bsum, int n){
  __shared__ int sm[4];
  int i = blockIdx.x*256 + threadIdx.x;
  int v = (i < n) ? (deg[i] + 1) : 0;
#pragma unroll
  for (int m = 1; m < 64; m <<= 1) v += __shfl_xor(v, m, 64);
  if ((threadIdx.x & 63) == 0) sm[threadIdx.x >> 6] = v;
  __syncthreads();
  if (threadIdx.x == 0) bsum[blockIdx.x] = sm[0] + sm[1] + sm[2] + sm[3];
}

// assumes nb <= 256 (N <= 65536). cs2[slot] = {src|batch<<27, eid}
__global__ void k_scan_apply(const int* __restrict__ deg, const int* __restrict__ bsum,
                             int* __restrict__ rowptr, int2* __restrict__ cs2,
                             const int* __restrict__ batch, float* __restrict__ gc,
                             int n, int nb){
  __shared__ int pre[256];
  __shared__ int sm[256];
  int t = threadIdx.x;
  int b = blockIdx.x;
  int pv = (t < nb) ? bsum[t] : 0;
  pre[t] = pv; __syncthreads();
#pragma unroll
  for (int off = 1; off < 256; off <<= 1){
    int x = (t >= off) ? pre[t - off] : 0;
    __syncthreads();
    pre[t] += x;
    __syncthreads();
  }
  int P = (b > 0) ? pre[b - 1] : 0;
  int i = b*256 + t;
  int v = (i < n) ? (deg[i] + 1) : 0;
  sm[t] = v; __syncthreads();
#pragma unroll
  for (int off = 1; off < 256; off <<= 1){
    int x = (t >= off) ? sm[t - off] : 0;
    __syncthreads();
    sm[t] += x;
    __syncthreads();
  }
  if (i < n){
    int r = P + sm[t] - v;
    rowptr[i] = r;
    cs2[r] = make_int2(i | (batch[i] << 27), 0);
  }
  if (b == nb - 1 && t == 255) rowptr[n] = P + sm[255];
  if (b == 0){
    gc[t] = 0.f;
    gc[t + 256] = 0.f;
  }
}

// atomic-free scatter: one 8B store per edge (src-tag + eid together)
__global__ void k_scatter(const int* __restrict__ src, const int* __restrict__ dst,
                          const int* __restrict__ batch,
                          const int* __restrict__ rowptr, const int* __restrict__ rank,
                          int2* __restrict__ cs2, int e){
  int i = (blockIdx.x*blockDim.x + threadIdx.x) * 4;
  if (i + 3 < e){
    int4 s4 = *(const int4*)&src[i];
    int4 d4 = *(const int4*)&dst[i];
    int4 r4 = *(const int4*)&rank[i];
    int p0 = rowptr[d4.x] + 1 + r4.x;
    int p1 = rowptr[d4.y] + 1 + r4.y;
    int p2 = rowptr[d4.z] + 1 + r4.z;
    int p3 = rowptr[d4.w] + 1 + r4.w;
    cs2[p0] = make_int2(s4.x | (batch[s4.x] << 27), i);
    cs2[p1] = make_int2(s4.y | (batch[s4.y] << 27), i + 1);
    cs2[p2] = make_int2(s4.z | (batch[s4.z] << 27), i + 2);
    cs2[p3] = make_int2(s4.w | (batch[s4.w] << 27), i + 3);
  } else {
    for (int j = i; j < e; ++j){
      int d = dst[j], sv = src[j];
      int pos = rowptr[d] + 1 + rank[j];
      cs2[pos] = make_int2(sv | (batch[sv] << 27), j);
    }
  }
}

// ------- node transforms via MFMA (layers 1,2): block = 64-node M-block -------
template<int K>
__global__ __launch_bounds__(256)
void k_node_transform(const float* __restrict__ h,
                      const float* __restrict__ Wl, const float* __restrict__ bl,
                      const float* __restrict__ Wr, const float* __restrict__ br,
                      const float* __restrict__ Wres, const float* __restrict__ bias,
                      unsigned short* __restrict__ xl8, float* __restrict__ xr,
                      float* __restrict__ res, int n){
  const int KH = K / 32;
  int lane = threadIdx.x & 63;
  int nt   = threadIdx.x >> 6;      // wave = N-tile 0..3
  int nn = lane & 15, q = lane >> 4;
  int m0 = blockIdx.x * 64;
  if (m0 >= n) return;
  bf16x8 Af[4][KH];
#pragma unroll
  for (int t = 0; t < 4; ++t){
#pragma unroll
    for (int kh = 0; kh < KH; ++kh){
      int node = min(m0 + t*16 + nn, n - 1);
      const float* hp = h + (size_t)node*K + kh*32 + q*8;
      Af[t][kh] = to_bf16x8(*(const float4*)hp, *(const float4*)(hp + 4));
    }
  }
  int n0 = nt * 16;
  for (int sel = 0; sel < 3; ++sel){
    const float* Wp = (sel == 0) ? Wl : (sel == 1) ? Wr : Wres;
    const float* bp = (sel == 0) ? bl : (sel == 1) ? br : bias;
    bf16x8 Bf[KH];
#pragma unroll
    for (int kh = 0; kh < KH; ++kh){
#pragma unroll
      for (int j = 0; j < 8; ++j)
        Bf[kh][j] = (short)bf16_of(Wp[(kh*32 + q*8 + j)*64 + n0 + nn]);
    }
    float bv = bp[n0 + nn];
#pragma unroll
    for (int t = 0; t < 4; ++t){
      floatx4 acc = {bv, bv, bv, bv};
#pragma unroll
      for (int kh = 0; kh < KH; ++kh)
        acc = __builtin_amdgcn_mfma_f32_16x16x32_bf16(Af[t][kh], Bf[kh], acc, 0, 0, 0);
      int nodeb = m0 + t*16 + q*4;   // + reg = node ; col = n0+nn
      if (sel == 0){
#pragma unroll
        for (int reg = 0; reg < 4; ++reg){
          float v = acc[reg];
          float p = __shfl_xor(v, 1, 64);
          int node = nodeb + reg;
          if (!(nn & 1) && node < n)
            xl8[(size_t)node*32 + ((n0 + nn) >> 1)] =
              (unsigned short)__builtin_amdgcn_cvt_pk_fp8_f32(v, p, 0, false);
        }
      } else {
        float* op = (sel == 1) ? xr : res;
#pragma unroll
        for (int reg = 0; reg < 4; ++reg){
          int node = nodeb + reg;
          if (node < n) op[(size_t)node*64 + n0 + nn] = acc[reg];
        }
      }
    }
  }
}

// --- fused edge softmax + LN + relu. 8 lanes/edge, prefetch-3 gather pipeline ---
__global__ void k_gat_edge(const uint2* __restrict__ xl_u2, const float* __restrict__ xr,
                           const float* __restrict__ att,
                           const float* __restrict__ lng, const float* __restrict__ lnb,
                           const int* __restrict__ rowptr, const int2* __restrict__ cs2,
                           float* __restrict__ hio, int n){
  int node = (blockIdx.x*blockDim.x + threadIdx.x) >> 6;
  int lane = threadIdx.x & 63;
  if (node >= n) return;
  int sub = lane >> 3;     // edge slot 0..7
  int l   = lane & 7;      // 8 dims per lane
  size_t base = (size_t)node*64 + 8*l;
  // hoisted: residual + xr loads issue before the gather loop
  float4 r0 = *(const float4*)&hio[base];
  float4 r1 = *(const float4*)&hio[base + 4];
  float4 xr0 = *(const float4*)&xr[base];
  float4 xr1 = *(const float4*)&xr[base + 4];
  float4 at0f = *(const float4*)&att[8*l];
  float4 at1f = *(const float4*)&att[8*l + 4];
  halfx2 xh0 = f22h2(xr0.x, xr0.y), xh1 = f22h2(xr0.z, xr0.w);
  halfx2 xh2 = f22h2(xr1.x, xr1.y), xh3 = f22h2(xr1.z, xr1.w);
  halfx2 at0 = f22h2(at0f.x*LOG2E, at0f.y*LOG2E);
  halfx2 at1 = f22h2(at0f.z*LOG2E, at0f.w*LOG2E);
  halfx2 at2 = f22h2(at1f.x*LOG2E, at1f.y*LOG2E);
  halfx2 at3 = f22h2(at1f.z*LOG2E, at1f.w*LOG2E);
  halfx2 z2  = {(_Float16)0.f, (_Float16)0.f};
  halfx2 c02 = {(_Float16)0.2f, (_Float16)0.2f};
  int p0 = rowptr[node], p1 = rowptr[node+1];
  int deg = p1 - p0;
  int sreg = cs2[p0 + min(lane, deg-1)].x;
  int rounds = (deg + 7) >> 3;
  float dsum = 0.f;
  float a0=0.f,a1=0.f,a2=0.f,a3=0.f,a4=0.f,a5=0.f,a6=0.f,a7=0.f;
  // prefetch-3: slots sub, 8+sub, 16+sub all issue in the prologue (parallel latencies)
  int e0 = sub;
  bool v0 = e0 < deg;
  int s0 = __shfl(sreg, v0 ? e0 : 0, 64) & NODE_MASK;
  uint2 x0 = xl_u2[(size_t)s0*8 + l];
  int e1 = 8 + sub;                 // < 64 always
  bool v1 = e1 < deg;
  uint2 x1 = x0;
  if (rounds > 1){
    int s1 = __shfl(sreg, v1 ? e1 : 0, 64) & NODE_MASK;
    x1 = xl_u2[(size_t)s1*8 + l];
  }
  int e2 = 16 + sub;                // < 64 always
  bool v2 = e2 < deg;
  uint2 x2 = x0;
  if (rounds > 2){
    int s2 = __shfl(sreg, v2 ? e2 : 0, 64) & NODE_MASK;
    x2 = xl_u2[(size_t)s2*8 + l];
  }
  for (int r = 0; r < rounds; ++r){
    int en = 8*(r+3) + sub;
    bool vn = en < deg;
    uint2 xn = x0;
    if (r + 3 < rounds){
      int sn;
      if (en < 64) sn = __shfl(sreg, vn ? en : 0, 64);
      else         sn = cs2[p0 + (vn ? en : 0)].x;
      sn &= NODE_MASK;
      xn = xl_u2[(size_t)sn*8 + l];
    }
    floatx2 p01 = __builtin_amdgcn_cvt_pk_f32_fp8(x0.x, false);
    floatx2 p23 = __builtin_amdgcn_cvt_pk_f32_fp8(x0.x, true);
    floatx2 p45 = __builtin_amdgcn_cvt_pk_f32_fp8(x0.y, false);
    floatx2 p67 = __builtin_amdgcn_cvt_pk_f32_fp8(x0.y, true);
    halfx2 v0h = f22h2(p01.x, p01.y) + xh0;
    halfx2 v1h = f22h2(p23.x, p23.y) + xh1;
    halfx2 v2h = f22h2(p45.x, p45.y) + xh2;
    halfx2 v3h = f22h2(p67.x, p67.y) + xh3;
    halfx2 lr0 = __builtin_elementwise_min(v0h, z2) * c02 + __builtin_elementwise_max(v0h, z2);
    halfx2 lr1 = __builtin_elementwise_min(v1h, z2) * c02 + __builtin_elementwise_max(v1h, z2);
    halfx2 lr2 = __builtin_elementwise_min(v2h, z2) * c02 + __builtin_elementwise_max(v2h, z2);
    halfx2 lr3 = __builtin_elementwise_min(v3h, z2) * c02 + __builtin_elementwise_max(v3h, z2);
    float partial = fdot2h(lr3, at3, fdot2h(lr2, at2, fdot2h(lr1, at1, fdot2h(lr0, at0, 0.f))));
#pragma unroll
    for (int mm = 1; mm < 8; mm <<= 1) partial += __shfl_xor(partial, mm, 64);
    float w = v0 ? exp2f(partial) : 0.f;
    dsum += w;
    a0 = fmaf(w, p01.x, a0);
    a1 = fmaf(w, p01.y, a1);
    a2 = fmaf(w, p23.x, a2);
    a3 = fmaf(w, p23.y, a3);
    a4 = fmaf(w, p45.x, a4);
    a5 = fmaf(w, p45.y, a5);
    a6 = fmaf(w, p67.x, a6);
    a7 = fmaf(w, p67.y, a7);
    x0 = x1; v0 = v1;
    x1 = x2; v1 = v2;
    x2 = xn; v2 = vn;
  }
#pragma unroll
  for (int off = 8; off < 64; off <<= 1){
    dsum += __shfl_xor(dsum, off, 64);
    a0 += __shfl_xor(a0, off, 64);
    a1 += __shfl_xor(a1, off, 64);
    a2 += __shfl_xor(a2, off, 64);
    a3 += __shfl_xor(a3, off, 64);
    a4 += __shfl_xor(a4, off, 64);
    a5 += __shfl_xor(a5, off, 64);
    a6 += __shfl_xor(a6, off, 64);
    a7 += __shfl_xor(a7, off, 64);
  }
  float inv = __builtin_amdgcn_rcpf(dsum);
  float o0 = fmaf(a0, inv, r0.x);
  float o1 = fmaf(a1, inv, r0.y);
  float o2 = fmaf(a2, inv, r0.z);
  float o3 = fmaf(a3, inv, r0.w);
  float o4 = fmaf(a4, inv, r1.x);
  float o5 = fmaf(a5, inv, r1.y);
  float o6 = fmaf(a6, inv, r1.z);
  float o7 = fmaf(a7, inv, r1.w);
  float mean = wave_sum(o0+o1+o2+o3+o4+o5+o6+o7) * (1.f/512.f);
  float d0 = o0-mean, d1 = o1-mean, d2 = o2-mean, d3 = o3-mean;
  float d4 = o4-mean, d5 = o5-mean, d6 = o6-mean, d7 = o7-mean;
  float var = wave_sum(d0*d0+d1*d1+d2*d2+d3*d3+d4*d4+d5*d5+d6*d6+d7*d7) * (1.f/512.f);
  float rstd = rsqrtf(var + 1e-5f);
  if (sub == 0){
    float4 lg0 = *(const float4*)&lng[8*l];
    float4 lg1 = *(const float4*)&lng[8*l + 4];
    float4 lb0 = *(const float4*)&lnb[8*l];
    float4 lb1 = *(const float4*)&lnb[8*l + 4];
    float4 out0, out1;
    out0.x = fmaxf(fmaf(d0*rstd, lg0.x, lb0.x), 0.f);
    out0.y = fmaxf(fmaf(d1*rstd, lg0.y, lb0.y), 0.f);
    out0.z = fmaxf(fmaf(d2*rstd, lg0.z, lb0.z), 0.f);
    out0.w = fmaxf(fmaf(d3*rstd, lg0.w, lb0.w), 0.f);
    out1.x = fmaxf(fmaf(d4*rstd, lg1.x, lb1.x), 0.f);
    out1.y = fmaxf(fmaf(d5*rstd, lg1.y, lb1.y), 0.f);
    out1.z = fmaxf(fmaf(d6*rstd, lg1.z, lb1.z), 0.f);
    out1.w = fmaxf(fmaf(d7*rstd, lg1.w, lb1.w), 0.f);
    *(float4*)&hio[base] = out0;
    *(float4*)&hio[base + 4] = out1;
  }
}

// ------- G[g] = gc[g] @ W1c + b1, packed half2 table; one graph per block -------
__global__ void k_graph_proj(const float* __restrict__ gc, const float* __restrict__ W1,
                             const float* __restrict__ b1, unsigned* __restrict__ Gh){
  int g = blockIdx.x;
  int j = threadIdx.x;      // 0..127
  float a = b1[j];
#pragma unroll 8
  for (int k = 0; k < 64; ++k) a = fmaf(gc[g*64+k], W1[(128+k)*128 + j], a);
  float p = __shfl_xor(a, 1, 64);
  if (!(j & 1)){
    halfx2 hv = f22h2(a, p);
    Gh[g*64 + (j >> 1)] = *(unsigned*)&hv;
  }
}

// ---- fused: node proj via MFMA (blocks 0..nt64-1) + global add pool (remaining blocks) ----
__global__ __launch_bounds__(256)
void k_node_proj_pool(const float* __restrict__ nr, const float* __restrict__ W1,
                      const int* __restrict__ batch,
                      unsigned short* __restrict__ Au16, unsigned* __restrict__ Bu,
                      float* __restrict__ gc, int n, int nt64){
  int lane = threadIdx.x & 63;
  int wave = threadIdx.x >> 6;      // 0..3
  if ((int)blockIdx.x >= nt64){
    // ---------------- pool role: one wave per 64 nodes, 8-batched loads ----------------
    int wid = (blockIdx.x - nt64)*4 + wave;
    int n0 = wid*64;
    if (n0 >= n) return;
    int n1 = min(n0 + 64, n);
    int last = n1 - 1 - n0;           // 0..63
    int bt = batch[min(n0 + lane, n - 1)];
    int curg = __shfl(bt, 0, 64);
    float s = 0.f;
#pragma unroll
    for (int bb = 0; bb < 64; bb += 8){
      if (bb > last) break;
      float v0_ = (bb+0 <= last) ? nr[(size_t)(n0+bb+0)*64 + lane] : 0.f;
      float v1_ = (bb+1 <= last) ? nr[(size_t)(n0+bb+1)*64 + lane] : 0.f;
      float v2_ = (bb+2 <= last) ? nr[(size_t)(n0+bb+2)*64 + lane] : 0.f;
      float v3_ = (bb+3 <= last) ? nr[(size_t)(n0+bb+3)*64 + lane] : 0.f;
      float v4_ = (bb+4 <= last) ? nr[(size_t)(n0+bb+4)*64 + lane] : 0.f;
      float v5_ = (bb+5 <= last) ? nr[(size_t)(n0+bb+5)*64 + lane] : 0.f;
      float v6_ = (bb+6 <= last) ? nr[(size_t)(n0+bb+6)*64 + lane] : 0.f;
      float v7_ = (bb+7 <= last) ? nr[(size_t)(n0+bb+7)*64 + lane] : 0.f;
#pragma unroll
      for (int j = 0; j < 8; ++j){
        int g = __shfl(bt, min(bb + j, last), 64);
        if (g != curg){ atomicAdd(&gc[curg*64 + lane], s); s = 0.f; curg = g; }
        float vj = (j==0)?v0_:(j==1)?v1_:(j==2)?v2_:(j==3)?v3_:
                   (j==4)?v4_:(j==5)?v5_:(j==6)?v6_:v7_;
        s += vj;
      }
    }
    atomicAdd(&gc[curg*64 + lane], s);
    return;
  }
  // ---------------- node proj role ----------------
  int nn = lane & 15, q = lane >> 4;
  int m0 = blockIdx.x * 64;
  bf16x8 Af[4][2];
#pragma unroll
  for (int t = 0; t < 4; ++t){
#pragma unroll
    for (int kh = 0; kh < 2; ++kh){
      int node = min(m0 + t*16 + nn, n - 1);
      const float* hp = nr + (size_t)node*64 + kh*32 + q*8;
      Af[t][kh] = to_bf16x8(*(const float4*)hp, *(const float4*)(hp + 4));
    }
  }
  for (int half = 0; half < 2; ++half){     // 0: W1a -> Au ; 1: W1b -> Bu
#pragma unroll
    for (int ni = 0; ni < 2; ++ni){
      int nt = wave + ni*4;
      int n0 = nt * 16;
      bf16x8 Bf[2];
#pragma unroll
      for (int kh = 0; kh < 2; ++kh){
#pragma unroll
        for (int j = 0; j < 8; ++j)
          Bf[kh][j] = (short)bf16_of(W1[(half*64 + kh*32 + q*8 + j)*128 + n0 + nn]);
      }
#pragma unroll
      for (int t = 0; t < 4; ++t){
        floatx4 acc = {0.f, 0.f, 0.f, 0.f};
#pragma unroll
        for (int kh = 0; kh < 2; ++kh)
          acc = __builtin_amdgcn_mfma_f32_16x16x32_bf16(Af[t][kh], Bf[kh], acc, 0, 0, 0);
        int nodeb = m0 + t*16 + q*4;
#pragma unroll
        for (int reg = 0; reg < 4; ++reg){
          float v = acc[reg];
          float p = __shfl_xor(v, 1, 64);
          int node = nodeb + reg;
          if (!(nn & 1) && node < n){
            int j = (n0 + nn) >> 1;
            if (half == 0)
              Au16[(size_t)node*64 + j] =
                (unsigned short)__builtin_amdgcn_cvt_pk_fp8_f32(v, p, 0, false);
            else
              Bu[(size_t)node*64 + j] = pack_bf16(v, p);
          }
        }
      }
    }
  }
}

// -- final per-edge MLP, dst-major, 8 lanes/edge, prefetch-3; writes out[eid] direct --
__global__ void k_edge_out_csr(const uint4* __restrict__ Au4, const uint4* __restrict__ Bu4,
                               const unsigned* __restrict__ Gh,
                               const int* __restrict__ rowptr, const int2* __restrict__ cs2,
                               const float* __restrict__ W2, const float* __restrict__ b2,
                               float* __restrict__ out, int n){
  int node = (blockIdx.x*blockDim.x + threadIdx.x) >> 6;
  int lane = threadIdx.x & 63;
  if (node >= n) return;
  int sub = lane >> 3;     // edge slot 0..7
  int l   = lane & 7;      // 16 dims per lane
  int p0 = rowptr[node];
  int deg2 = rowptr[node+1] - p0 - 1;
  if (deg2 <= 0) return;
  int2 slot = cs2[p0 + 1 + min(lane, deg2-1)];
  int sreg = slot.x;
  int ereg = slot.y;
  uint4 ba = Bu4[(size_t)node*16 + 2*l];
  uint4 bb = Bu4[(size_t)node*16 + 2*l + 1];
  float2 t0 = unpack_bf16(ba.x), t1 = unpack_bf16(ba.y);
  float2 t2 = unpack_bf16(ba.z), t3 = unpack_bf16(ba.w);
  float2 t4 = unpack_bf16(bb.x), t5 = unpack_bf16(bb.y);
  float2 t6 = unpack_bf16(bb.z), t7 = unpack_bf16(bb.w);
  halfx2 bh0 = f22h2(t0.x, t0.y), bh1 = f22h2(t1.x, t1.y);
  halfx2 bh2 = f22h2(t2.x, t2.y), bh3 = f22h2(t3.x, t3.y);
  halfx2 bh4 = f22h2(t4.x, t4.y), bh5 = f22h2(t5.x, t5.y);
  halfx2 bh6 = f22h2(t6.x, t6.y), bh7 = f22h2(t7.x, t7.y);
  float4 w0 = *(const float4*)&W2[16*l];
  float4 w1 = *(const float4*)&W2[16*l + 4];
  float4 w2 = *(const float4*)&W2[16*l + 8];
  float4 w3 = *(const float4*)&W2[16*l + 12];
  halfx2 wh0 = f22h2(w0.x, w0.y), wh1 = f22h2(w0.z, w0.w);
  halfx2 wh2 = f22h2(w1.x, w1.y), wh3 = f22h2(w1.z, w1.w);
  halfx2 wh4 = f22h2(w2.x, w2.y), wh5 = f22h2(w2.z, w2.w);
  halfx2 wh6 = f22h2(w3.x, w3.y), wh7 = f22h2(w3.z, w3.w);
  halfx2 z2 = {(_Float16)0.f, (_Float16)0.f};
  float b2v = b2[0];
  int rounds = (deg2 + 7) >> 3;
  // prefetch-3 pipeline
  int e0 = sub;
  bool v0 = e0 < deg2;
  int q0 = v0 ? e0 : 0;
  int c0 = __shfl(sreg, q0, 64);
  int id0 = __shfl(ereg, q0, 64);
  uint4 A0 = Au4[(size_t)(c0 & NODE_MASK)*8 + l];
  int e1 = 8 + sub;                 // < 64 always
  bool v1 = e1 < deg2;
  int c1 = c0, id1 = id0; uint4 A1 = A0;
  if (rounds > 1){
    int q1 = v1 ? e1 : 0;
    c1 = __shfl(sreg, q1, 64);
    id1 = __shfl(ereg, q1, 64);
    A1 = Au4[(size_t)(c1 & NODE_MASK)*8 + l];
  }
  int e2 = 16 + sub;                // < 64 always
  bool v2 = e2 < deg2;
  int c2 = c0, id2 = id0; uint4 A2 = A0;
  if (rounds > 2){
    int q2 = v2 ? e2 : 0;
    c2 = __shfl(sreg, q2, 64);
    id2 = __shfl(ereg, q2, 64);
    A2 = Au4[(size_t)(c2 & NODE_MASK)*8 + l];
  }
  for (int r = 0; r < rounds; ++r){
    int en = 8*(r+3) + sub;
    bool vn = en < deg2;
    int cn = c0, idn = id0; uint4 An = A0;
    if (r + 3 < rounds){
      int qn = vn ? en : 0;
      if (en < 64){ cn = __shfl(sreg, qn, 64); idn = __shfl(ereg, qn, 64); }
      else        { int2 sv = cs2[p0 + 1 + qn]; cn = sv.x; idn = sv.y; }
      An = Au4[(size_t)(cn & NODE_MASK)*8 + l];
    }
    int g = ((unsigned)c0) >> 27;
    const uint4* gp = (const uint4*)(Gh + g*64 + 8*l);
    uint4 g0 = gp[0], g1 = gp[1];
    halfx2 gh0 = *(halfx2*)&g0.x, gh1 = *(halfx2*)&g0.y;
    halfx2 gh2 = *(halfx2*)&g0.z, gh3 = *(halfx2*)&g0.w;
    halfx2 gh4 = *(halfx2*)&g1.x, gh5 = *(halfx2*)&g1.y;
    halfx2 gh6 = *(halfx2*)&g1.z, gh7 = *(halfx2*)&g1.w;
    floatx2 a01 = __builtin_amdgcn_cvt_pk_f32_fp8(A0.x, false);
    floatx2 a23 = __builtin_amdgcn_cvt_pk_f32_fp8(A0.x, true);
    floatx2 a45 = __builtin_amdgcn_cvt_pk_f32_fp8(A0.y, false);
    floatx2 a67 = __builtin_amdgcn_cvt_pk_f32_fp8(A0.y, true);
    floatx2 a89 = __builtin_amdgcn_cvt_pk_f32_fp8(A0.z, false);
    floatx2 aab = __builtin_amdgcn_cvt_pk_f32_fp8(A0.z, true);
    floatx2 acd = __builtin_amdgcn_cvt_pk_f32_fp8(A0.w, false);
    floatx2 aef = __builtin_amdgcn_cvt_pk_f32_fp8(A0.w, true);
    halfx2 h0 = __builtin_elementwise_max(f22h2(a01.x, a01.y) + bh0 + gh0, z2);
    halfx2 h1 = __builtin_elementwise_max(f22h2(a23.x, a23.y) + bh1 + gh1, z2);
    halfx2 h2 = __builtin_elementwise_max(f22h2(a45.x, a45.y) + bh2 + gh2, z2);
    halfx2 h3 = __builtin_elementwise_max(f22h2(a67.x, a67.y) + bh3 + gh3, z2);
    halfx2 h4 = __builtin_elementwise_max(f22h2(a89.x, a89.y) + bh4 + gh4, z2);
    halfx2 h5 = __builtin_elementwise_max(f22h2(aab.x, aab.y) + bh5 + gh5, z2);
    halfx2 h6 = __builtin_elementwise_max(f22h2(acd.x, acd.y) + bh6 + gh6, z2);
    halfx2 h7 = __builtin_elementwise_max(f22h2(aef.x, aef.y) + bh7 + gh7, z2);
    float part = fdot2h(h7, wh7, fdot2h(h6, wh6, fdot2h(h5, wh5, fdot2h(h4, wh4,
                 fdot2h(h3, wh3, fdot2h(h2, wh2, fdot2h(h1, wh1, fdot2h(h0, wh0, 0.f))))))));
#pragma unroll
    for (int mm = 1; mm < 8; mm <<= 1) part += __shfl_xor(part, mm, 64);
    if (l == 0 && v0) out[id0] = part + b2v;
    c0 = c1; id0 = id1; A0 = A1; v0 = v1;
    c1 = c2; id1 = id2; A1 = A2; v1 = v2;
    c2 = cn; id2 = idn; A2 = An; v2 = vn;
  }
}

extern "C" void kernel_launch(void* const* d_in, const int* in_sizes, int n_in,
                              void* d_out, int out_size, void* d_ws, size_t ws_size,
                              hipStream_t stream){
  const float* x     = (const float*)d_in[0];
  const int*   ei    = (const int*)d_in[1];
  const int*   batch = (const int*)d_in[2];
  const int N = in_sizes[2];
  const int E = in_sizes[1] / 2;
  const int* src = ei;
  const int* dst = ei + E;

  unsigned* W = (unsigned*)d_ws;
  const size_t N16 = (size_t)N * 16;
  const size_t N32 = (size_t)N * 32;
  const size_t N64 = (size_t)N * 64;
  unsigned short* xl8 = (unsigned short*)W;          // N x 64 fp8 (N16 dwords)
  float* xr = (float*)(W + N16);
  float* hE = (float*)(W + N16 + N64);
  float* hD = (float*)(W + N16 + 2*N64);
  unsigned short* Au16 = (unsigned short*)W;         // overlap (xl8/xr dead by readout)
  unsigned* Bu = W + N32;                            // overlap (hE dead by readout)
  int* rowptr = (int*)(W + N16 + 3*N64);             // N+16
  int* deg    = rowptr + (N + 16);                   // N
  int2* cs2   = (int2*)(deg + N);                    // N+E {src|batch<<27, eid}  (8B aligned: offset even)
  int* rank   = (int*)(cs2 + (N + E));               // E
  float* gc   = (float*)(rank + E);                  // 8*64
  unsigned* Gh = (unsigned*)(gc + 512);              // 8*64 packed half2
  int* bsum   = (int*)(Gh + 512);                    // ceil(N/256)

  const int NB = (N + 255) / 256;
  const int NT64 = (N + 63) / 64;
  const int ECH = (E/4 + 255) / 256;

  // ---- CSR build || layer-0 transform ----
  (void)hipMemsetAsync(deg, 0, (size_t)N*4, stream);
  const float* Wl0   = (const float*)d_in[3];
  const float* bl0   = (const float*)d_in[4];
  const float* Wr0   = (const float*)d_in[5];
  const float* br0   = (const float*)d_in[6];
  const float* Wres0 = (const float*)d_in[8];
  const float* bias0 = (const float*)d_in[9];
  k_deg_t0 <<<NT64 + ECH, 256, 0, stream>>>(dst, deg, rank, E,
                                            x, Wl0, bl0, Wr0, br0, Wres0, bias0,
                                            xl8, xr, hD, N, NT64);
  k_scan_reduce<<<NB, 256, 0, stream>>>(deg, bsum, N);
  k_scan_apply <<<NB, 256, 0, stream>>>(deg, bsum, rowptr, cs2, batch, gc, N, NB);
  k_scatter    <<<ECH, 256, 0, stream>>>(src, dst, batch, rowptr, rank, cs2, E);

  // ---- 3 GATv2 layers (layer-0 transform already done) ----
  const float* h = hD;
  float* hn = hD;
  for (int l = 0; l < 3; ++l){
    const float* Wl   = (const float*)d_in[3 + 9*l + 0];
    const float* bl   = (const float*)d_in[3 + 9*l + 1];
    const float* Wr   = (const float*)d_in[3 + 9*l + 2];
    const float* br   = (const float*)d_in[3 + 9*l + 3];
    const float* att  = (const float*)d_in[3 + 9*l + 4];
    const float* Wres = (const float*)d_in[3 + 9*l + 5];
    const float* bias = (const float*)d_in[3 + 9*l + 6];
    const float* lng  = (const float*)d_in[3 + 9*l + 7];
    const float* lnb  = (const float*)d_in[3 + 9*l + 8];
    if (l > 0)
      k_node_transform<64><<<NT64, 256, 0, stream>>>(h, Wl, bl, Wr, br, Wres, bias, xl8, xr, hn, N);
    k_gat_edge<<<(N+3)/4, 256, 0, stream>>>((const uint2*)xl8, xr, att, lng, lnb, rowptr, cs2, hn, N);
    h = hn;
    hn = (l == 0) ? hE : hD;   // final node_repr = hD
  }

  // ---- readout ----
  const float* W1 = (const float*)d_in[30];
  const float* b1 = (const float*)d_in[31];
  const float* W2 = (const float*)d_in[32];
  const float* b2 = (const float*)d_in[33];

  int pool_waves = (N + 63) / 64;
  int poolB = (pool_waves + 3) / 4;
  k_node_proj_pool<<<NT64 + poolB, 256, 0, stream>>>(hD, W1, batch, Au16, Bu, gc, N, NT64);
  k_graph_proj<<<8, 128, 0, stream>>>(gc, W1, b1, Gh);
  k_edge_out_csr<<<(N+3)/4, 256, 0, stream>>>((const uint4*)Au16, (const uint4*)Bu, Gh,
                                              rowptr, cs2, W2, b2, (float*)d_out, N);
}

// Round 11
// 378.592 us; speedup vs baseline: 1.0358x; 1.0358x over previous
//
#include <hip/hip_runtime.h>
#include <math.h>

typedef float floatx2 __attribute__((ext_vector_type(2)));
typedef float floatx4 __attribute__((ext_vector_type(4)));
typedef short bf16x8 __attribute__((ext_vector_type(8)));
typedef _Float16 halfx2 __attribute__((ext_vector_type(2)));

#define NODE_MASK 0x07FFFFFF
#define LOG2E 1.4426950408889634f
#define DEG_STRIDE 16   // one 64B line per counter (round-7 best-measured config)

__device__ __forceinline__ float wave_sum(float v){
#pragma unroll
  for (int m = 1; m < 64; m <<= 1) v += __shfl_xor(v, m, 64);
  return v;
}

__device__ __forceinline__ unsigned short bf16_of(float a){
  unsigned ua = __float_as_uint(a);
  ua = (ua + 0x7FFFu + ((ua >> 16) & 1u)) >> 16;
  return (unsigned short)ua;
}
__device__ __forceinline__ unsigned pack_bf16(float a, float b){
  unsigned ua = __float_as_uint(a), ub = __float_as_uint(b);
  ua = (ua + 0x7FFFu + ((ua >> 16) & 1u)) >> 16;
  ub = (ub + 0x7FFFu + ((ub >> 16) & 1u)) >> 16;
  return ua | (ub << 16);
}
__device__ __forceinline__ float2 unpack_bf16(unsigned p){
  float2 r;
  r.x = __uint_as_float(p << 16);
  r.y = __uint_as_float(p & 0xFFFF0000u);
  return r;
}
__device__ __forceinline__ bf16x8 to_bf16x8(float4 a, float4 b){
  bf16x8 r;
  r[0]=(short)bf16_of(a.x); r[1]=(short)bf16_of(a.y);
  r[2]=(short)bf16_of(a.z); r[3]=(short)bf16_of(a.w);
  r[4]=(short)bf16_of(b.x); r[5]=(short)bf16_of(b.y);
  r[6]=(short)bf16_of(b.z); r[7]=(short)bf16_of(b.w);
  return r;
}
__device__ __forceinline__ halfx2 f22h2(float a, float b){
  auto r = __builtin_amdgcn_cvt_pkrtz(a, b);
  return *(halfx2*)&r;
}
__device__ __forceinline__ float fdot2h(halfx2 a, halfx2 b, float c){
  return __builtin_amdgcn_fdot2(a, b, c, false);
}

// ---- merged: deg_rank (blocks >= NT64) || layer-0 node transform (blocks < NT64) ----
__global__ __launch_bounds__(256)
void k_deg_t0(const int* __restrict__ dst, int* __restrict__ deg16, int* __restrict__ rank, int e,
              const float* __restrict__ h,
              const float* __restrict__ Wl, const float* __restrict__ bl,
              const float* __restrict__ Wr, const float* __restrict__ br,
              const float* __restrict__ Wres, const float* __restrict__ bias,
              unsigned short* __restrict__ xl8, float* __restrict__ xr,
              float* __restrict__ res, int n, int nt64){
  if ((int)blockIdx.x >= nt64){
    int c = blockIdx.x - nt64;
    int i = (c*256 + (int)threadIdx.x)*4;
    if (i + 3 < e){
      int4 d4 = *(const int4*)&dst[i];
      int4 r4;
      r4.x = atomicAdd(&deg16[d4.x*DEG_STRIDE], 1);
      r4.y = atomicAdd(&deg16[d4.y*DEG_STRIDE], 1);
      r4.z = atomicAdd(&deg16[d4.z*DEG_STRIDE], 1);
      r4.w = atomicAdd(&deg16[d4.w*DEG_STRIDE], 1);
      *(int4*)&rank[i] = r4;
    } else {
      for (int j = i; j < e; ++j) rank[j] = atomicAdd(&deg16[dst[j]*DEG_STRIDE], 1);
    }
    return;
  }
  const int K = 32, KH = 1;
  int lane = threadIdx.x & 63;
  int nt   = threadIdx.x >> 6;
  int nn = lane & 15, q = lane >> 4;
  int m0 = blockIdx.x * 64;
  if (m0 >= n) return;
  bf16x8 Af[4][KH];
#pragma unroll
  for (int t = 0; t < 4; ++t){
#pragma unroll
    for (int kh = 0; kh < KH; ++kh){
      int node = min(m0 + t*16 + nn, n - 1);
      const float* hp = h + (size_t)node*K + kh*32 + q*8;
      Af[t][kh] = to_bf16x8(*(const float4*)hp, *(const float4*)(hp + 4));
    }
  }
  int n0 = nt * 16;
  for (int sel = 0; sel < 3; ++sel){
    const float* Wp = (sel == 0) ? Wl : (sel == 1) ? Wr : Wres;
    const float* bp = (sel == 0) ? bl : (sel == 1) ? br : bias;
    bf16x8 Bf[KH];
#pragma unroll
    for (int kh = 0; kh < KH; ++kh){
#pragma unroll
      for (int j = 0; j < 8; ++j)
        Bf[kh][j] = (short)bf16_of(Wp[(kh*32 + q*8 + j)*64 + n0 + nn]);
    }
    float bv = bp[n0 + nn];
#pragma unroll
    for (int t = 0; t < 4; ++t){
      floatx4 acc = {bv, bv, bv, bv};
#pragma unroll
      for (int kh = 0; kh < KH; ++kh)
        acc = __builtin_amdgcn_mfma_f32_16x16x32_bf16(Af[t][kh], Bf[kh], acc, 0, 0, 0);
      int nodeb = m0 + t*16 + q*4;
      if (sel == 0){
#pragma unroll
        for (int reg = 0; reg < 4; ++reg){
          float v = acc[reg];
          float p = __shfl_xor(v, 1, 64);
          int node = nodeb + reg;
          if (!(nn & 1) && node < n)
            xl8[(size_t)node*32 + ((n0 + nn) >> 1)] =
              (unsigned short)__builtin_amdgcn_cvt_pk_fp8_f32(v, p, 0, false);
        }
      } else {
        float* op = (sel == 1) ? xr : res;
#pragma unroll
        for (int reg = 0; reg < 4; ++reg){
          int node = nodeb + reg;
          if (node < n) op[(size_t)node*64 + n0 + nn] = acc[reg];
        }
      }
    }
  }
}

// block-sum of (deg+1) -> bsum[b]
__global__ void k_scan_reduce(const int* __restrict__ deg16, int* __restrict__ bsum, int n){
  __shared__ int sm[4];
  int i = blockIdx.x*256 + threadIdx.x;
  int v = (i < n) ? (deg16[i*DEG_STRIDE] + 1) : 0;
#pragma unroll
  for (int m = 1; m < 64; m <<= 1) v += __shfl_xor(v, m, 64);
  if ((threadIdx.x & 63) == 0) sm[threadIdx.x >> 6] = v;
  __syncthreads();
  if (threadIdx.x == 0) bsum[blockIdx.x] = sm[0] + sm[1] + sm[2] + sm[3];
}

// assumes nb <= 256 (N <= 65536). cs2[slot] = {src|batch<<27, eid}
__global__ void k_scan_apply(const int* __restrict__ deg16, const int* __restrict__ bsum,
                             int* __restrict__ rowptr, int2* __restrict__ cs2,
                             const int* __restrict__ batch, float* __restrict__ gc,
                             int n, int nb){
  __shared__ int pre[256];
  __shared__ int sm[256];
  int t = threadIdx.x;
  int b = blockIdx.x;
  int pv = (t < nb) ? bsum[t] : 0;
  pre[t] = pv; __syncthreads();
#pragma unroll
  for (int off = 1; off < 256; off <<= 1){
    int x = (t >= off) ? pre[t - off] : 0;
    __syncthreads();
    pre[t] += x;
    __syncthreads();
  }
  int P = (b > 0) ? pre[b - 1] : 0;
  int i = b*256 + t;
  int v = (i < n) ? (deg16[i*DEG_STRIDE] + 1) : 0;
  sm[t] = v; __syncthreads();
#pragma unroll
  for (int off = 1; off < 256; off <<= 1){
    int x = (t >= off) ? sm[t - off] : 0;
    __syncthreads();
    sm[t] += x;
    __syncthreads();
  }
  if (i < n){
    int r = P + sm[t] - v;
    rowptr[i] = r;
    cs2[r] = make_int2(i | (batch[i] << 27), 0);
  }
  if (b == nb - 1 && t == 255) rowptr[n] = P + sm[255];
  if (b == 0){
    gc[t] = 0.f;
    gc[t + 256] = 0.f;
  }
}

// atomic-free scatter: one 8B store per edge (src-tag + eid together)
__global__ void k_scatter(const int* __restrict__ src, const int* __restrict__ dst,
                          const int* __restrict__ batch,
                          const int* __restrict__ rowptr, const int* __restrict__ rank,
                          int2* __restrict__ cs2, int e){
  int i = (blockIdx.x*blockDim.x + threadIdx.x) * 4;
  if (i + 3 < e){
    int4 s4 = *(const int4*)&src[i];
    int4 d4 = *(const int4*)&dst[i];
    int4 r4 = *(const int4*)&rank[i];
    int p0 = rowptr[d4.x] + 1 + r4.x;
    int p1 = rowptr[d4.y] + 1 + r4.y;
    int p2 = rowptr[d4.z] + 1 + r4.z;
    int p3 = rowptr[d4.w] + 1 + r4.w;
    cs2[p0] = make_int2(s4.x | (batch[s4.x] << 27), i);
    cs2[p1] = make_int2(s4.y | (batch[s4.y] << 27), i + 1);
    cs2[p2] = make_int2(s4.z | (batch[s4.z] << 27), i + 2);
    cs2[p3] = make_int2(s4.w | (batch[s4.w] << 27), i + 3);
  } else {
    for (int j = i; j < e; ++j){
      int d = dst[j], sv = src[j];
      int pos = rowptr[d] + 1 + rank[j];
      cs2[pos] = make_int2(sv | (batch[sv] << 27), j);
    }
  }
}

// ------- node transforms via MFMA (layers 1,2): block = 64-node M-block -------
template<int K>
__global__ __launch_bounds__(256)
void k_node_transform(const float* __restrict__ h,
                      const float* __restrict__ Wl, const float* __restrict__ bl,
                      const float* __restrict__ Wr, const float* __restrict__ br,
                      const float* __restrict__ Wres, const float* __restrict__ bias,
                      unsigned short* __restrict__ xl8, float* __restrict__ xr,
                      float* __restrict__ res, int n){
  const int KH = K / 32;
  int lane = threadIdx.x & 63;
  int nt   = threadIdx.x >> 6;      // wave = N-tile 0..3
  int nn = lane & 15, q = lane >> 4;
  int m0 = blockIdx.x * 64;
  if (m0 >= n) return;
  bf16x8 Af[4][KH];
#pragma unroll
  for (int t = 0; t < 4; ++t){
#pragma unroll
    for (int kh = 0; kh < KH; ++kh){
      int node = min(m0 + t*16 + nn, n - 1);
      const float* hp = h + (size_t)node*K + kh*32 + q*8;
      Af[t][kh] = to_bf16x8(*(const float4*)hp, *(const float4*)(hp + 4));
    }
  }
  int n0 = nt * 16;
  for (int sel = 0; sel < 3; ++sel){
    const float* Wp = (sel == 0) ? Wl : (sel == 1) ? Wr : Wres;
    const float* bp = (sel == 0) ? bl : (sel == 1) ? br : bias;
    bf16x8 Bf[KH];
#pragma unroll
    for (int kh = 0; kh < KH; ++kh){
#pragma unroll
      for (int j = 0; j < 8; ++j)
        Bf[kh][j] = (short)bf16_of(Wp[(kh*32 + q*8 + j)*64 + n0 + nn]);
    }
    float bv = bp[n0 + nn];
#pragma unroll
    for (int t = 0; t < 4; ++t){
      floatx4 acc = {bv, bv, bv, bv};
#pragma unroll
      for (int kh = 0; kh < KH; ++kh)
        acc = __builtin_amdgcn_mfma_f32_16x16x32_bf16(Af[t][kh], Bf[kh], acc, 0, 0, 0);
      int nodeb = m0 + t*16 + q*4;   // + reg = node ; col = n0+nn
      if (sel == 0){
#pragma unroll
        for (int reg = 0; reg < 4; ++reg){
          float v = acc[reg];
          float p = __shfl_xor(v, 1, 64);
          int node = nodeb + reg;
          if (!(nn & 1) && node < n)
            xl8[(size_t)node*32 + ((n0 + nn) >> 1)] =
              (unsigned short)__builtin_amdgcn_cvt_pk_fp8_f32(v, p, 0, false);
        }
      } else {
        float* op = (sel == 1) ? xr : res;
#pragma unroll
        for (int reg = 0; reg < 4; ++reg){
          int node = nodeb + reg;
          if (node < n) op[(size_t)node*64 + n0 + nn] = acc[reg];
        }
      }
    }
  }
}

// --- fused edge softmax + LN + relu. 8 lanes/edge, prefetch-2; residual load hoisted ---
__global__ void k_gat_edge(const uint2* __restrict__ xl_u2, const float* __restrict__ xr,
                           const float* __restrict__ att,
                           const float* __restrict__ lng, const float* __restrict__ lnb,
                           const int* __restrict__ rowptr, const int2* __restrict__ cs2,
                           float* __restrict__ hio, int n){
  int node = (blockIdx.x*blockDim.x + threadIdx.x) >> 6;
  int lane = threadIdx.x & 63;
  if (node >= n) return;
  int sub = lane >> 3;     // edge slot 0..7
  int l   = lane & 7;      // 8 dims per lane
  size_t base = (size_t)node*64 + 8*l;
  // hoisted: residual + xr loads issue before the gather loop
  float4 r0 = *(const float4*)&hio[base];
  float4 r1 = *(const float4*)&hio[base + 4];
  float4 xr0 = *(const float4*)&xr[base];
  float4 xr1 = *(const float4*)&xr[base + 4];
  float4 at0f = *(const float4*)&att[8*l];
  float4 at1f = *(const float4*)&att[8*l + 4];
  halfx2 xh0 = f22h2(xr0.x, xr0.y), xh1 = f22h2(xr0.z, xr0.w);
  halfx2 xh2 = f22h2(xr1.x, xr1.y), xh3 = f22h2(xr1.z, xr1.w);
  halfx2 at0 = f22h2(at0f.x*LOG2E, at0f.y*LOG2E);
  halfx2 at1 = f22h2(at0f.z*LOG2E, at0f.w*LOG2E);
  halfx2 at2 = f22h2(at1f.x*LOG2E, at1f.y*LOG2E);
  halfx2 at3 = f22h2(at1f.z*LOG2E, at1f.w*LOG2E);
  halfx2 z2  = {(_Float16)0.f, (_Float16)0.f};
  halfx2 c02 = {(_Float16)0.2f, (_Float16)0.2f};
  int p0 = rowptr[node], p1 = rowptr[node+1];
  int deg = p1 - p0;
  int sreg = cs2[p0 + min(lane, deg-1)].x;
  int rounds = (deg + 7) >> 3;
  float dsum = 0.f;
  float a0=0.f,a1=0.f,a2=0.f,a3=0.f,a4=0.f,a5=0.f,a6=0.f,a7=0.f;
  int e0 = sub;
  bool v0 = e0 < deg;
  int s0 = __shfl(sreg, v0 ? e0 : 0, 64) & NODE_MASK;
  uint2 x0 = xl_u2[(size_t)s0*8 + l];
  int e1 = 8 + sub;                 // always < 64
  bool v1 = e1 < deg;
  uint2 x1 = x0;
  if (rounds > 1){
    int s1 = __shfl(sreg, v1 ? e1 : 0, 64) & NODE_MASK;
    x1 = xl_u2[(size_t)s1*8 + l];
  }
  for (int r = 0; r < rounds; ++r){
    int en = 8*(r+2) + sub;
    bool vn = en < deg;
    uint2 xn = x0;
    if (r + 2 < rounds){
      int sn;
      if (en < 64) sn = __shfl(sreg, vn ? en : 0, 64);
      else         sn = cs2[p0 + (vn ? en : 0)].x;
      sn &= NODE_MASK;
      xn = xl_u2[(size_t)sn*8 + l];
    }
    floatx2 p01 = __builtin_amdgcn_cvt_pk_f32_fp8(x0.x, false);
    floatx2 p23 = __builtin_amdgcn_cvt_pk_f32_fp8(x0.x, true);
    floatx2 p45 = __builtin_amdgcn_cvt_pk_f32_fp8(x0.y, false);
    floatx2 p67 = __builtin_amdgcn_cvt_pk_f32_fp8(x0.y, true);
    halfx2 v0h = f22h2(p01.x, p01.y) + xh0;
    halfx2 v1h = f22h2(p23.x, p23.y) + xh1;
    halfx2 v2h = f22h2(p45.x, p45.y) + xh2;
    halfx2 v3h = f22h2(p67.x, p67.y) + xh3;
    halfx2 lr0 = __builtin_elementwise_min(v0h, z2) * c02 + __builtin_elementwise_max(v0h, z2);
    halfx2 lr1 = __builtin_elementwise_min(v1h, z2) * c02 + __builtin_elementwise_max(v1h, z2);
    halfx2 lr2 = __builtin_elementwise_min(v2h, z2) * c02 + __builtin_elementwise_max(v2h, z2);
    halfx2 lr3 = __builtin_elementwise_min(v3h, z2) * c02 + __builtin_elementwise_max(v3h, z2);
    float partial = fdot2h(lr3, at3, fdot2h(lr2, at2, fdot2h(lr1, at1, fdot2h(lr0, at0, 0.f))));
#pragma unroll
    for (int mm = 1; mm < 8; mm <<= 1) partial += __shfl_xor(partial, mm, 64);
    float w = v0 ? exp2f(partial) : 0.f;
    dsum += w;
    a0 = fmaf(w, p01.x, a0);
    a1 = fmaf(w, p01.y, a1);
    a2 = fmaf(w, p23.x, a2);
    a3 = fmaf(w, p23.y, a3);
    a4 = fmaf(w, p45.x, a4);
    a5 = fmaf(w, p45.y, a5);
    a6 = fmaf(w, p67.x, a6);
    a7 = fmaf(w, p67.y, a7);
    x0 = x1; v0 = v1;
    x1 = xn; v1 = vn;
  }
#pragma unroll
  for (int off = 8; off < 64; off <<= 1){
    dsum += __shfl_xor(dsum, off, 64);
    a0 += __shfl_xor(a0, off, 64);
    a1 += __shfl_xor(a1, off, 64);
    a2 += __shfl_xor(a2, off, 64);
    a3 += __shfl_xor(a3, off, 64);
    a4 += __shfl_xor(a4, off, 64);
    a5 += __shfl_xor(a5, off, 64);
    a6 += __shfl_xor(a6, off, 64);
    a7 += __shfl_xor(a7, off, 64);
  }
  float inv = __builtin_amdgcn_rcpf(dsum);
  float o0 = fmaf(a0, inv, r0.x);
  float o1 = fmaf(a1, inv, r0.y);
  float o2 = fmaf(a2, inv, r0.z);
  float o3 = fmaf(a3, inv, r0.w);
  float o4 = fmaf(a4, inv, r1.x);
  float o5 = fmaf(a5, inv, r1.y);
  float o6 = fmaf(a6, inv, r1.z);
  float o7 = fmaf(a7, inv, r1.w);
  float mean = wave_sum(o0+o1+o2+o3+o4+o5+o6+o7) * (1.f/512.f);
  float d0 = o0-mean, d1 = o1-mean, d2 = o2-mean, d3 = o3-mean;
  float d4 = o4-mean, d5 = o5-mean, d6 = o6-mean, d7 = o7-mean;
  float var = wave_sum(d0*d0+d1*d1+d2*d2+d3*d3+d4*d4+d5*d5+d6*d6+d7*d7) * (1.f/512.f);
  float rstd = rsqrtf(var + 1e-5f);
  if (sub == 0){
    float4 lg0 = *(const float4*)&lng[8*l];
    float4 lg1 = *(const float4*)&lng[8*l + 4];
    float4 lb0 = *(const float4*)&lnb[8*l];
    float4 lb1 = *(const float4*)&lnb[8*l + 4];
    float4 out0, out1;
    out0.x = fmaxf(fmaf(d0*rstd, lg0.x, lb0.x), 0.f);
    out0.y = fmaxf(fmaf(d1*rstd, lg0.y, lb0.y), 0.f);
    out0.z = fmaxf(fmaf(d2*rstd, lg0.z, lb0.z), 0.f);
    out0.w = fmaxf(fmaf(d3*rstd, lg0.w, lb0.w), 0.f);
    out1.x = fmaxf(fmaf(d4*rstd, lg1.x, lb1.x), 0.f);
    out1.y = fmaxf(fmaf(d5*rstd, lg1.y, lb1.y), 0.f);
    out1.z = fmaxf(fmaf(d6*rstd, lg1.z, lb1.z), 0.f);
    out1.w = fmaxf(fmaf(d7*rstd, lg1.w, lb1.w), 0.f);
    *(float4*)&hio[base] = out0;
    *(float4*)&hio[base + 4] = out1;
  }
}

// ------- G[g] = gc[g] @ W1c + b1, packed half2 table; one graph per block -------
__global__ void k_graph_proj(const float* __restrict__ gc, const float* __restrict__ W1,
                             const float* __restrict__ b1, unsigned* __restrict__ Gh){
  int g = blockIdx.x;
  int j = threadIdx.x;      // 0..127
  float a = b1[j];
#pragma unroll 8
  for (int k = 0; k < 64; ++k) a = fmaf(gc[g*64+k], W1[(128+k)*128 + j], a);
  float p = __shfl_xor(a, 1, 64);
  if (!(j & 1)){
    halfx2 hv = f22h2(a, p);
    Gh[g*64 + (j >> 1)] = *(unsigned*)&hv;
  }
}

// ---- fused: node proj via MFMA (blocks 0..nt64-1) + global add pool (remaining blocks) ----
__global__ __launch_bounds__(256)
void k_node_proj_pool(const float* __restrict__ nr, const float* __restrict__ W1,
                      const int* __restrict__ batch,
                      unsigned short* __restrict__ Au16, unsigned* __restrict__ Bu,
                      float* __restrict__ gc, int n, int nt64){
  int lane = threadIdx.x & 63;
  int wave = threadIdx.x >> 6;      // 0..3
  if ((int)blockIdx.x >= nt64){
    // ---------------- pool role: one wave per 64 nodes, 8-batched loads ----------------
    int wid = (blockIdx.x - nt64)*4 + wave;
    int n0 = wid*64;
    if (n0 >= n) return;
    int n1 = min(n0 + 64, n);
    int last = n1 - 1 - n0;           // 0..63
    int bt = batch[min(n0 + lane, n - 1)];
    int curg = __shfl(bt, 0, 64);
    float s = 0.f;
#pragma unroll
    for (int bb = 0; bb < 64; bb += 8){
      if (bb > last) break;
      float v0_ = (bb+0 <= last) ? nr[(size_t)(n0+bb+0)*64 + lane] : 0.f;
      float v1_ = (bb+1 <= last) ? nr[(size_t)(n0+bb+1)*64 + lane] : 0.f;
      float v2_ = (bb+2 <= last) ? nr[(size_t)(n0+bb+2)*64 + lane] : 0.f;
      float v3_ = (bb+3 <= last) ? nr[(size_t)(n0+bb+3)*64 + lane] : 0.f;
      float v4_ = (bb+4 <= last) ? nr[(size_t)(n0+bb+4)*64 + lane] : 0.f;
      float v5_ = (bb+5 <= last) ? nr[(size_t)(n0+bb+5)*64 + lane] : 0.f;
      float v6_ = (bb+6 <= last) ? nr[(size_t)(n0+bb+6)*64 + lane] : 0.f;
      float v7_ = (bb+7 <= last) ? nr[(size_t)(n0+bb+7)*64 + lane] : 0.f;
#pragma unroll
      for (int j = 0; j < 8; ++j){
        int g = __shfl(bt, min(bb + j, last), 64);
        if (g != curg){ atomicAdd(&gc[curg*64 + lane], s); s = 0.f; curg = g; }
        float vj = (j==0)?v0_:(j==1)?v1_:(j==2)?v2_:(j==3)?v3_:
                   (j==4)?v4_:(j==5)?v5_:(j==6)?v6_:v7_;
        s += vj;
      }
    }
    atomicAdd(&gc[curg*64 + lane], s);
    return;
  }
  // ---------------- node proj role ----------------
  int nn = lane & 15, q = lane >> 4;
  int m0 = blockIdx.x * 64;
  bf16x8 Af[4][2];
#pragma unroll
  for (int t = 0; t < 4; ++t){
#pragma unroll
    for (int kh = 0; kh < 2; ++kh){
      int node = min(m0 + t*16 + nn, n - 1);
      const float* hp = nr + (size_t)node*64 + kh*32 + q*8;
      Af[t][kh] = to_bf16x8(*(const float4*)hp, *(const float4*)(hp + 4));
    }
  }
  for (int half = 0; half < 2; ++half){     // 0: W1a -> Au ; 1: W1b -> Bu
#pragma unroll
    for (int ni = 0; ni < 2; ++ni){
      int nt = wave + ni*4;
      int n0 = nt * 16;
      bf16x8 Bf[2];
#pragma unroll
      for (int kh = 0; kh < 2; ++kh){
#pragma unroll
        for (int j = 0; j < 8; ++j)
          Bf[kh][j] = (short)bf16_of(W1[(half*64 + kh*32 + q*8 + j)*128 + n0 + nn]);
      }
#pragma unroll
      for (int t = 0; t < 4; ++t){
        floatx4 acc = {0.f, 0.f, 0.f, 0.f};
#pragma unroll
        for (int kh = 0; kh < 2; ++kh)
          acc = __builtin_amdgcn_mfma_f32_16x16x32_bf16(Af[t][kh], Bf[kh], acc, 0, 0, 0);
        int nodeb = m0 + t*16 + q*4;
#pragma unroll
        for (int reg = 0; reg < 4; ++reg){
          float v = acc[reg];
          float p = __shfl_xor(v, 1, 64);
          int node = nodeb + reg;
          if (!(nn & 1) && node < n){
            int j = (n0 + nn) >> 1;
            if (half == 0)
              Au16[(size_t)node*64 + j] =
                (unsigned short)__builtin_amdgcn_cvt_pk_fp8_f32(v, p, 0, false);
            else
              Bu[(size_t)node*64 + j] = pack_bf16(v, p);
          }
        }
      }
    }
  }
}

// -- final per-edge MLP, dst-major, 8 lanes/edge; cs2 gives {src,eid} in one load --
__global__ void k_edge_out_csr(const uint4* __restrict__ Au4, const uint4* __restrict__ Bu4,
                               const unsigned* __restrict__ Gh,
                               const int* __restrict__ rowptr, const int2* __restrict__ cs2,
                               const float* __restrict__ W2, const float* __restrict__ b2,
                               float* __restrict__ out, int n){
  int node = (blockIdx.x*blockDim.x + threadIdx.x) >> 6;
  int lane = threadIdx.x & 63;
  if (node >= n) return;
  int sub = lane >> 3;     // edge slot 0..7
  int l   = lane & 7;      // 16 dims per lane
  int p0 = rowptr[node];
  int deg2 = rowptr[node+1] - p0 - 1;
  if (deg2 <= 0) return;
  int2 slot = cs2[p0 + 1 + min(lane, deg2-1)];
  int sreg = slot.x;
  int ereg = slot.y;
  uint4 ba = Bu4[(size_t)node*16 + 2*l];
  uint4 bb = Bu4[(size_t)node*16 + 2*l + 1];
  float2 t0 = unpack_bf16(ba.x), t1 = unpack_bf16(ba.y);
  float2 t2 = unpack_bf16(ba.z), t3 = unpack_bf16(ba.w);
  float2 t4 = unpack_bf16(bb.x), t5 = unpack_bf16(bb.y);
  float2 t6 = unpack_bf16(bb.z), t7 = unpack_bf16(bb.w);
  halfx2 bh0 = f22h2(t0.x, t0.y), bh1 = f22h2(t1.x, t1.y);
  halfx2 bh2 = f22h2(t2.x, t2.y), bh3 = f22h2(t3.x, t3.y);
  halfx2 bh4 = f22h2(t4.x, t4.y), bh5 = f22h2(t5.x, t5.y);
  halfx2 bh6 = f22h2(t6.x, t6.y), bh7 = f22h2(t7.x, t7.y);
  float4 w0 = *(const float4*)&W2[16*l];
  float4 w1 = *(const float4*)&W2[16*l + 4];
  float4 w2 = *(const float4*)&W2[16*l + 8];
  float4 w3 = *(const float4*)&W2[16*l + 12];
  halfx2 wh0 = f22h2(w0.x, w0.y), wh1 = f22h2(w0.z, w0.w);
  halfx2 wh2 = f22h2(w1.x, w1.y), wh3 = f22h2(w1.z, w1.w);
  halfx2 wh4 = f22h2(w2.x, w2.y), wh5 = f22h2(w2.z, w2.w);
  halfx2 wh6 = f22h2(w3.x, w3.y), wh7 = f22h2(w3.z, w3.w);
  halfx2 z2 = {(_Float16)0.f, (_Float16)0.f};
  float b2v = b2[0];
  int rounds = (deg2 + 7) >> 3;
  int e0 = sub;
  bool v0 = e0 < deg2;
  int q0 = v0 ? e0 : 0;
  int c0 = __shfl(sreg, q0, 64);
  int id0 = __shfl(ereg, q0, 64);
  uint4 A0 = Au4[(size_t)(c0 & NODE_MASK)*8 + l];
  int e1 = 8 + sub;                 // always < 64
  bool v1 = e1 < deg2;
  int c1 = c0, id1 = id0; uint4 A1 = A0;
  if (rounds > 1){
    int q1 = v1 ? e1 : 0;
    c1 = __shfl(sreg, q1, 64);
    id1 = __shfl(ereg, q1, 64);
    A1 = Au4[(size_t)(c1 & NODE_MASK)*8 + l];
  }
  for (int r = 0; r < rounds; ++r){
    int en = 8*(r+2) + sub;
    bool vn = en < deg2;
    int cn = c0, idn = id0; uint4 An = A0;
    if (r + 2 < rounds){
      int qn = vn ? en : 0;
      if (en < 64){ cn = __shfl(sreg, qn, 64); idn = __shfl(ereg, qn, 64); }
      else        { int2 sv = cs2[p0 + 1 + qn]; cn = sv.x; idn = sv.y; }
      An = Au4[(size_t)(cn & NODE_MASK)*8 + l];
    }
    int g = ((unsigned)c0) >> 27;
    const uint4* gp = (const uint4*)(Gh + g*64 + 8*l);
    uint4 g0 = gp[0], g1 = gp[1];
    halfx2 gh0 = *(halfx2*)&g0.x, gh1 = *(halfx2*)&g0.y;
    halfx2 gh2 = *(halfx2*)&g0.z, gh3 = *(halfx2*)&g0.w;
    halfx2 gh4 = *(halfx2*)&g1.x, gh5 = *(halfx2*)&g1.y;
    halfx2 gh6 = *(halfx2*)&g1.z, gh7 = *(halfx2*)&g1.w;
    floatx2 a01 = __builtin_amdgcn_cvt_pk_f32_fp8(A0.x, false);
    floatx2 a23 = __builtin_amdgcn_cvt_pk_f32_fp8(A0.x, true);
    floatx2 a45 = __builtin_amdgcn_cvt_pk_f32_fp8(A0.y, false);
    floatx2 a67 = __builtin_amdgcn_cvt_pk_f32_fp8(A0.y, true);
    floatx2 a89 = __builtin_amdgcn_cvt_pk_f32_fp8(A0.z, false);
    floatx2 aab = __builtin_amdgcn_cvt_pk_f32_fp8(A0.z, true);
    floatx2 acd = __builtin_amdgcn_cvt_pk_f32_fp8(A0.w, false);
    floatx2 aef = __builtin_amdgcn_cvt_pk_f32_fp8(A0.w, true);
    halfx2 h0 = __builtin_elementwise_max(f22h2(a01.x, a01.y) + bh0 + gh0, z2);
    halfx2 h1 = __builtin_elementwise_max(f22h2(a23.x, a23.y) + bh1 + gh1, z2);
    halfx2 h2 = __builtin_elementwise_max(f22h2(a45.x, a45.y) + bh2 + gh2, z2);
    halfx2 h3 = __builtin_elementwise_max(f22h2(a67.x, a67.y) + bh3 + gh3, z2);
    halfx2 h4 = __builtin_elementwise_max(f22h2(a89.x, a89.y) + bh4 + gh4, z2);
    halfx2 h5 = __builtin_elementwise_max(f22h2(aab.x, aab.y) + bh5 + gh5, z2);
    halfx2 h6 = __builtin_elementwise_max(f22h2(acd.x, acd.y) + bh6 + gh6, z2);
    halfx2 h7 = __builtin_elementwise_max(f22h2(aef.x, aef.y) + bh7 + gh7, z2);
    float part = fdot2h(h7, wh7, fdot2h(h6, wh6, fdot2h(h5, wh5, fdot2h(h4, wh4,
                 fdot2h(h3, wh3, fdot2h(h2, wh2, fdot2h(h1, wh1, fdot2h(h0, wh0, 0.f))))))));
#pragma unroll
    for (int mm = 1; mm < 8; mm <<= 1) part += __shfl_xor(part, mm, 64);
    if (l == 0 && v0) out[id0] = part + b2v;
    c0 = c1; id0 = id1; A0 = A1; v0 = v1;
    c1 = cn; id1 = idn; A1 = An; v1 = vn;
  }
}

extern "C" void kernel_launch(void* const* d_in, const int* in_sizes, int n_in,
                              void* d_out, int out_size, void* d_ws, size_t ws_size,
                              hipStream_t stream){
  const float* x     = (const float*)d_in[0];
  const int*   ei    = (const int*)d_in[1];
  const int*   batch = (const int*)d_in[2];
  const int N = in_sizes[2];
  const int E = in_sizes[1] / 2;
  const int* src = ei;
  const int* dst = ei + E;

  unsigned* W = (unsigned*)d_ws;
  const size_t N16 = (size_t)N * 16;
  const size_t N32 = (size_t)N * 32;
  const size_t N64 = (size_t)N * 64;
  unsigned short* xl8 = (unsigned short*)W;          // N x 64 fp8 (N16 dwords)
  float* xr = (float*)(W + N16);
  float* hE = (float*)(W + N16 + N64);
  float* hD = (float*)(W + N16 + 2*N64);
  unsigned short* Au16 = (unsigned short*)W;         // overlap (xl8/xr dead by readout)
  unsigned* Bu = W + N32;                            // overlap (hE dead by readout)
  int* rowptr = (int*)(W + N16 + 3*N64);             // N+16
  int* deg16  = rowptr + (N + 16);                   // 16*N (one line per counter)
  int2* cs2   = (int2*)(deg16 + (size_t)16*N);       // N+E {src|batch<<27, eid}
  int* rank   = (int*)(cs2 + (N + E));               // E
  float* gc   = (float*)(rank + E);                  // 8*64
  unsigned* Gh = (unsigned*)(gc + 512);              // 8*64 packed half2
  int* bsum   = (int*)(Gh + 512);                    // ceil(N/256)

  const int NB = (N + 255) / 256;
  const int NT64 = (N + 63) / 64;
  const int ECH = (E/4 + 255) / 256;

  // ---- CSR build || layer-0 transform ----
  (void)hipMemsetAsync(deg16, 0, (size_t)N*16*4, stream);
  const float* Wl0   = (const float*)d_in[3];
  const float* bl0   = (const float*)d_in[4];
  const float* Wr0   = (const float*)d_in[5];
  const float* br0   = (const float*)d_in[6];
  const float* Wres0 = (const float*)d_in[8];
  const float* bias0 = (const float*)d_in[9];
  k_deg_t0 <<<NT64 + ECH, 256, 0, stream>>>(dst, deg16, rank, E,
                                            x, Wl0, bl0, Wr0, br0, Wres0, bias0,
                                            xl8, xr, hD, N, NT64);
  k_scan_reduce<<<NB, 256, 0, stream>>>(deg16, bsum, N);
  k_scan_apply <<<NB, 256, 0, stream>>>(deg16, bsum, rowptr, cs2, batch, gc, N, NB);
  k_scatter    <<<ECH, 256, 0, stream>>>(src, dst, batch, rowptr, rank, cs2, E);

  // ---- 3 GATv2 layers (layer-0 transform already done) ----
  const float* h = hD;
  float* hn = hD;
  for (int l = 0; l < 3; ++l){
    const float* Wl   = (const float*)d_in[3 + 9*l + 0];
    const float* bl   = (const float*)d_in[3 + 9*l + 1];
    const float* Wr   = (const float*)d_in[3 + 9*l + 2];
    const float* br   = (const float*)d_in[3 + 9*l + 3];
    const float* att  = (const float*)d_in[3 + 9*l + 4];
    const float* Wres = (const float*)d_in[3 + 9*l + 5];
    const float* bias = (const float*)d_in[3 + 9*l + 6];
    const float* lng  = (const float*)d_in[3 + 9*l + 7];
    const float* lnb  = (const float*)d_in[3 + 9*l + 8];
    if (l > 0)
      k_node_transform<64><<<NT64, 256, 0, stream>>>(h, Wl, bl, Wr, br, Wres, bias, xl8, xr, hn, N);
    k_gat_edge<<<(N+3)/4, 256, 0, stream>>>((const uint2*)xl8, xr, att, lng, lnb, rowptr, cs2, hn, N);
    h = hn;
    hn = (l == 0) ? hE : hD;   // final node_repr = hD
  }

  // ---- readout ----
  const float* W1 = (const float*)d_in[30];
  const float* b1 = (const float*)d_in[31];
  const float* W2 = (const float*)d_in[32];
  const float* b2 = (const float*)d_in[33];

  int pool_waves = (N + 63) / 64;
  int poolB = (pool_waves + 3) / 4;
  k_node_proj_pool<<<NT64 + poolB, 256, 0, stream>>>(hD, W1, batch, Au16, Bu, gc, N, NT64);
  k_graph_proj<<<8, 128, 0, stream>>>(gc, W1, b1, Gh);
  k_edge_out_csr<<<(N+3)/4, 256, 0, stream>>>((const uint4*)Au16, (const uint4*)Bu, Gh,
                                              rowptr, cs2, W2, b2, (float*)d_out, N);
}